// Round 9
// baseline (114.570 us; speedup 1.0000x reference)
//
#include <hip/hip_runtime.h>
#include <hip/hip_bf16.h>
#include <stdint.h>

// Problem constants
#define BB 2
#define NN 2048
#define DIMM 1024
#define HEADS 16
#define DH 64
#define E3 3072   // 3*DIM
#define LOG2E_ 1.44269504088896f
#define THR_ 8.0f

typedef __bf16 bf16;
typedef __attribute__((ext_vector_type(8))) __bf16 bf16x8;
typedef __attribute__((ext_vector_type(4))) __bf16 bf16x4;
typedef __attribute__((ext_vector_type(4))) float f32x4;

// global -> LDS direct copy, 16B per lane. LDS dest must be wave-uniform base;
// HW adds lane*16. Global src is per-lane.
__device__ __forceinline__ void gload_lds16(const void* gsrc, void* ldst) {
  __builtin_amdgcn_global_load_lds(
      (const __attribute__((address_space(1))) uint32_t*)(uintptr_t)gsrc,
      (__attribute__((address_space(3))) uint32_t*)(uintptr_t)ldst,
      16, 0, 0);
}

// ---------------------------------------------------------------------------
// Kernel 1: fp32 -> bf16 conversion for x, w_qkv, w_out (fused)
// ---------------------------------------------------------------------------
__global__ __launch_bounds__(256)
void convert_all(const float* __restrict__ x, const float* __restrict__ wqkv,
                 const float* __restrict__ wout,
                 bf16* __restrict__ xb, bf16* __restrict__ wqb, bf16* __restrict__ wob) {
  size_t i = (size_t)blockIdx.x * blockDim.x + threadIdx.x;
  const float* src;
  bf16* dst;
  size_t off;
  if (i < 1048576u) { src = x; dst = xb; off = i; }
  else if (i < 1048576u + 786432u) { src = wqkv; dst = wqb; off = i - 1048576u; }
  else { src = wout; dst = wob; off = i - (1048576u + 786432u); }
  float4 v = ((const float4*)src)[off];
  bf16x4 o;
  o[0] = (bf16)v.x; o[1] = (bf16)v.y; o[2] = (bf16)v.z; o[3] = (bf16)v.w;
  *(bf16x4*)(dst + off * 4) = o;
}

// ---------------------------------------------------------------------------
// Kernel 2/4: C[m][n] = sum_k A[m][k] * Bw[n][k]   (B^T-input GEMM), K = 1024
// OUTMODE 0: bf16 store (qkv), Q columns (n<1024) pre-scaled by 0.125 (exact).
// OUTMODE 1: f32 store + bias (final output).
// ---------------------------------------------------------------------------
template <int OUTMODE>
__global__ __launch_bounds__(256)
void gemm_bt(const bf16* __restrict__ A, const bf16* __restrict__ Bw,
             void* __restrict__ Cout, const float* __restrict__ bias, int ldc) {
  const int tid = threadIdx.x;
  const int w = tid >> 6;
  const int lane = tid & 63;
  const int c = lane & 15;
  const int g = lane >> 4;
  const int wr = w >> 1, wc = w & 1;
  const int m0 = blockIdx.y * 128;
  const int n0 = blockIdx.x * 128;

  __shared__ __align__(16) char smem[16384];
  char* As = smem;
  char* Bs = smem + 8192;

  f32x4 acc[4][4] = {};

  for (int kt = 0; kt < 1024; kt += 32) {
    __syncthreads();
#pragma unroll
    for (int it = 0; it < 2; ++it) {
      int t = it * 256 + tid;
      int row = t >> 2, cc = t & 3;
      gload_lds16(A + (size_t)(m0 + row) * 1024 + kt + cc * 8, As + it * 4096 + w * 1024);
      gload_lds16(Bw + (size_t)(n0 + row) * 1024 + kt + cc * 8, Bs + it * 4096 + w * 1024);
    }
    __syncthreads();

    bf16x8 af[4], bfr[4];
#pragma unroll
    for (int i = 0; i < 4; ++i)
      af[i] = *(const bf16x8*)(As + ((wr * 64 + i * 16 + c) * 32 + g * 8) * 2);
#pragma unroll
    for (int j = 0; j < 4; ++j)
      bfr[j] = *(const bf16x8*)(Bs + ((wc * 64 + j * 16 + c) * 32 + g * 8) * 2);
#pragma unroll
    for (int i = 0; i < 4; ++i)
#pragma unroll
      for (int j = 0; j < 4; ++j)
        acc[i][j] = __builtin_amdgcn_mfma_f32_16x16x32_bf16(af[i], bfr[j], acc[i][j], 0, 0, 0);
  }

  if (OUTMODE == 0) {
    const float qsc = (n0 < 1024) ? 0.125f : 1.0f;
    bf16* C = (bf16*)Cout;
#pragma unroll
    for (int i = 0; i < 4; ++i) {
      int row = m0 + wr * 64 + i * 16 + g * 4;
#pragma unroll
      for (int j = 0; j < 4; ++j) {
        int col = n0 + wc * 64 + j * 16 + c;
#pragma unroll
        for (int r = 0; r < 4; ++r)
          C[(size_t)(row + r) * ldc + col] = (bf16)(acc[i][j][r] * qsc);
      }
    }
  } else {
    float* C = (float*)Cout;
#pragma unroll
    for (int i = 0; i < 4; ++i) {
      int row = m0 + wr * 64 + i * 16 + g * 4;
#pragma unroll
      for (int j = 0; j < 4; ++j) {
        int col = n0 + wc * 64 + j * 16 + c;
        float bv = bias[col];
#pragma unroll
        for (int r = 0; r < 4; ++r)
          C[(size_t)(row + r) * ldc + col] = acc[i][j][r] + bv;
      }
    }
  }
}

// ---------------------------------------------------------------------------
// Kernel 3: fused flash attention — swapped-operand, 2-deep pipeline (T15).
// 4 waves x 32 q-rows, grid 512, __launch_bounds__(256,2) (grid caps 2
// blocks/CU; take the 256-VGPR budget).
// LDS: K[2] @0,8192 (chunk XOR-swizzled rows); V[4] @16384+8192*i
// (tr-read subtile layout). Iteration t: stage(t+1); softmax-reduce(t-1);
// issue kf(t)+trV(t-1); softmax-exp(t-1); lgkm(15); QK(t); lgkm(0); PV(t-1);
// barrier. All buffer indices compile-time via macro instantiation.
// NOTE: lgkmcnt is a 4-bit field (max 15). With 8 kf + 16 tr issued in
// order, lgkmcnt(15) completes the 9 oldest = all 8 kf + 1 tr. (16 was a
// compile error in round 8.)
// ---------------------------------------------------------------------------
#define DSR128(dst, base, off) \
  asm volatile("ds_read_b128 %0, %1 offset:%c2" : "=v"(dst) : "v"(base), "i"(off))
#define DSTR(dst, base, off) \
  asm volatile("ds_read_b64_tr_b16 %0, %1 offset:%c2" : "=v"(dst) : "v"(base), "i"(off))

#define KF_ALL(KB) \
  DSR128(kf[0][0], kb0, (KB)*8192 + 0);    DSR128(kf[0][1], kb1, (KB)*8192 + 0); \
  DSR128(kf[1][0], kb0, (KB)*8192 + 2048); DSR128(kf[1][1], kb1, (KB)*8192 + 2048); \
  DSR128(kf[2][0], kb0, (KB)*8192 + 4096); DSR128(kf[2][1], kb1, (KB)*8192 + 4096); \
  DSR128(kf[3][0], kb0, (KB)*8192 + 6144); DSR128(kf[3][1], kb1, (KB)*8192 + 6144);

#define TRPAIR(f, ks, VP) \
  DSTR(tlo[f][ks], tb, (VP)*8192 + (f)*2048 + (ks)*1024); \
  DSTR(thi[f][ks], tb, (VP)*8192 + (f)*2048 + (ks)*1024 + 512);
#define TR_ALL(VP) \
  TRPAIR(0,0,VP) TRPAIR(0,1,VP) TRPAIR(1,0,VP) TRPAIR(1,1,VP) \
  TRPAIR(2,0,VP) TRPAIR(2,1,VP) TRPAIR(3,0,VP) TRPAIR(3,1,VP)

// max-reduce + defer-rescale (has __shfl -> DS ops; call only when lgkm empty)
#define SMAX_A(SPRV, qc) { \
  f32x4 vm = SPRV[0][qc]; \
  _Pragma("unroll") for (int j = 1; j < 4; ++j) \
    _Pragma("unroll") for (int r = 0; r < 4; ++r) vm[r] = fmaxf(vm[r], SPRV[j][qc][r]); \
  float rmax = fmaxf(fmaxf(vm[0], vm[1]), fmaxf(vm[2], vm[3])); \
  rmax = fmaxf(rmax, __shfl_xor(rmax, 16, 64)); \
  rmax = fmaxf(rmax, __shfl_xor(rmax, 32, 64)); \
  const float rmax2 = rmax * LOG2E_; \
  if (!__all(rmax2 <= mrun[qc] + THR_)) { \
    const float mnew = fmaxf(mrun[qc], rmax2); \
    const float fac = __builtin_amdgcn_exp2f(mrun[qc] - mnew); \
    mrun[qc] = mnew; \
    _Pragma("unroll") for (int f = 0; f < 4; ++f) oacc[f][qc] *= fac; \
    lacc[qc] *= fac; \
  } }

// exp + bf16 pack (pure VALU/TRANS — covers outstanding ds latency)
#define SMAX_B(SPRV, qc) { \
  const float negm = -mrun[qc]; \
  f32x4 p[4]; \
  _Pragma("unroll") for (int j = 0; j < 4; ++j) \
    _Pragma("unroll") for (int r = 0; r < 4; ++r) \
      p[j][r] = __builtin_amdgcn_exp2f(fmaf(SPRV[j][qc][r], LOG2E_, negm)); \
  _Pragma("unroll") for (int ks = 0; ks < 2; ++ks) \
    _Pragma("unroll") for (int r = 0; r < 4; ++r) { \
      vb[qc][ks][r] = (bf16)p[ks][r]; vb[qc][ks][4 + r] = (bf16)p[ks + 2][r]; \
    } }

#define QK_ALL(SCUR) \
  _Pragma("unroll") for (int j = 0; j < 4; ++j) { \
    f32x4 z = {0.f, 0.f, 0.f, 0.f}; \
    f32x4 s0 = __builtin_amdgcn_mfma_f32_16x16x32_bf16(kf[j][0], qf[0][0], z, 0, 0, 0); \
    s0 = __builtin_amdgcn_mfma_f32_16x16x32_bf16(kf[j][1], qf[0][1], s0, 0, 0, 0); \
    SCUR[j][0] = s0; \
    f32x4 s1 = __builtin_amdgcn_mfma_f32_16x16x32_bf16(kf[j][0], qf[1][0], z, 0, 0, 0); \
    s1 = __builtin_amdgcn_mfma_f32_16x16x32_bf16(kf[j][1], qf[1][1], s1, 0, 0, 0); \
    SCUR[j][1] = s1; }

#define PV_ALL() \
  _Pragma("unroll") for (int f = 0; f < 4; ++f) \
    _Pragma("unroll") for (int ks = 0; ks < 2; ++ks) { \
      bf16x8 va; \
      _Pragma("unroll") for (int e = 0; e < 4; ++e) { va[e] = tlo[f][ks][e]; va[4+e] = thi[f][ks][e]; } \
      oacc[f][0] = __builtin_amdgcn_mfma_f32_16x16x32_bf16(va, vb[0][ks], oacc[f][0], 0, 0, 0); \
      oacc[f][1] = __builtin_amdgcn_mfma_f32_16x16x32_bf16(va, vb[1][ks], oacc[f][1], 0, 0, 0); \
    } \
  lacc[0] = __builtin_amdgcn_mfma_f32_16x16x32_bf16(ones, vb[0][0], lacc[0], 0, 0, 0); \
  lacc[0] = __builtin_amdgcn_mfma_f32_16x16x32_bf16(ones, vb[0][1], lacc[0], 0, 0, 0); \
  lacc[1] = __builtin_amdgcn_mfma_f32_16x16x32_bf16(ones, vb[1][0], lacc[1], 0, 0, 0); \
  lacc[1] = __builtin_amdgcn_mfma_f32_16x16x32_bf16(ones, vb[1][1], lacc[1], 0, 0, 0);

#define STEP(KB, VN, VP, SCUR, SPRV, DOSTAGE, DOPREV) { \
  if (DOSTAGE) { \
    gload_lds16(pK0, smem + ((KB)^1)*8192 + w*1024); \
    gload_lds16(pK1, smem + ((KB)^1)*8192 + 4096 + w*1024); \
    gload_lds16(pV0, smem + 16384 + (VN)*8192 + w*1024); \
    gload_lds16(pV1, smem + 16384 + (VN)*8192 + 4096 + w*1024); \
    pK0 += 64*E3; pK1 += 64*E3; pV0 += 64*E3; pV1 += 64*E3; \
  } \
  if (DOPREV) { SMAX_A(SPRV, 0); SMAX_A(SPRV, 1); } \
  __builtin_amdgcn_sched_barrier(0); \
  KF_ALL(KB); \
  if (DOPREV) { TR_ALL(VP); } \
  if (DOPREV) { SMAX_B(SPRV, 0); SMAX_B(SPRV, 1); } \
  if (DOPREV) { asm volatile("s_waitcnt lgkmcnt(15)" ::: "memory"); } \
  else        { asm volatile("s_waitcnt lgkmcnt(0)" ::: "memory"); } \
  __builtin_amdgcn_sched_barrier(0); \
  __builtin_amdgcn_s_setprio(1); \
  QK_ALL(SCUR); \
  __builtin_amdgcn_s_setprio(0); \
  if (DOPREV) { \
    asm volatile("s_waitcnt lgkmcnt(0)" ::: "memory"); \
    __builtin_amdgcn_sched_barrier(0); \
    __builtin_amdgcn_s_setprio(1); \
    PV_ALL(); \
    __builtin_amdgcn_s_setprio(0); \
  } \
  __syncthreads(); \
}

__global__ __launch_bounds__(256, 2)
void flash_attn(const bf16* __restrict__ qkv, bf16* __restrict__ attb) {
  int bid = blockIdx.x;
  bid = (bid & 7) * 64 + (bid >> 3);  // XCD chunk swizzle (512 % 8 == 0)
  const int tid = threadIdx.x;
  const int w = tid >> 6;
  const int lane = tid & 63;
  const int c = lane & 15;
  const int g = lane >> 4;
  const int qt = bid & 15;            // 16 q-tiles of 128 rows
  const int bh = bid >> 4;
  const int b = bh >> 4;
  const int h = bh & 15;
  const int q0 = qt * 128 + w * 32;

  __shared__ __align__(16) char smem[49152];
  const uint32_t smem32 = (uint32_t)(uintptr_t)smem;

  // loop-invariant LDS read bases
  const uint32_t kb0 = smem32 + c * 128 + ((g ^ (c & 7)) * 16);
  const uint32_t kb1 = smem32 + c * 128 + (((4 + g) ^ (c & 7)) * 16);
  const uint32_t tb  = smem32 + 16384 + lane * 8;

  // Q B-frags (2 qcol tiles per wave)
  bf16x8 qf[2][2];
#pragma unroll
  for (int qc = 0; qc < 2; ++qc) {
    const size_t qbase = (size_t)(b * NN + q0 + qc * 16 + c) * E3 + h * 64;
    qf[qc][0] = *(const bf16x8*)(qkv + qbase + g * 8);
    qf[qc][1] = *(const bf16x8*)(qkv + qbase + 32 + g * 8);
  }

  bf16x8 ones;
#pragma unroll
  for (int e = 0; e < 8; ++e) ones[e] = (bf16)1.0f;

  // Staging source pointers (per-thread), advance one 64-key tile per stage.
  const bf16 *pK0, *pK1, *pV0, *pV1;
  {
    int tK0 = tid, tK1 = 256 + tid;
    int r0 = tK0 >> 3, s0 = (tK0 & 7) ^ (r0 & 7);
    int r1 = tK1 >> 3, s1 = (tK1 & 7) ^ (r1 & 7);
    pK0 = qkv + (size_t)(b * NN + r0) * E3 + 1024 + h * 64 + s0 * 8;
    pK1 = qkv + (size_t)(b * NN + r1) * E3 + 1024 + h * 64 + s1 * 8;
    int sv0 = tid, sv1 = 256 + tid;
    int f0 = sv0 >> 7, ks0 = (sv0 >> 6) & 1, o0 = (sv0 >> 5) & 1,
        g0 = (sv0 >> 3) & 3, j0 = (sv0 >> 1) & 3, i0 = sv0 & 1;
    int f1 = sv1 >> 7, ks1 = (sv1 >> 6) & 1, o1 = (sv1 >> 5) & 1,
        g1 = (sv1 >> 3) & 3, j1 = (sv1 >> 1) & 3, i1 = sv1 & 1;
    int key0 = 32 * o0 + 16 * ks0 + 4 * g0 + j0;
    int key1 = 32 * o1 + 16 * ks1 + 4 * g1 + j1;
    pV0 = qkv + (size_t)(b * NN + key0) * E3 + 2048 + h * 64 + f0 * 16 + i0 * 8;
    pV1 = qkv + (size_t)(b * NN + key1) * E3 + 2048 + h * 64 + f1 * 16 + i1 * 8;
  }

  f32x4 oacc[4][2] = {};
  f32x4 lacc[2] = {};
  float mrun[2] = {-1e30f, -1e30f};
  f32x4 sA[4][2], sB[4][2];
  bf16x8 kf[4][2];
  bf16x4 tlo[4][2], thi[4][2];
  bf16x8 vb[2][2];

  // prologue: stage tile 0 -> K[0], V[0]
  gload_lds16(pK0, smem + w * 1024);
  gload_lds16(pK1, smem + 4096 + w * 1024);
  gload_lds16(pV0, smem + 16384 + w * 1024);
  gload_lds16(pV1, smem + 16384 + 4096 + w * 1024);
  pK0 += 64 * E3; pK1 += 64 * E3; pV0 += 64 * E3; pV1 += 64 * E3;
  __syncthreads();

  STEP(0, 1, 0, sA, sB, 1, 0)                 // t = 0
  for (int to = 1; to <= 25; to += 4) {
    STEP(1, 2, 0, sB, sA, 1, 1)               // t ≡ 1 (mod 4)
    STEP(0, 3, 1, sA, sB, 1, 1)               // t ≡ 2
    STEP(1, 0, 2, sB, sA, 1, 1)               // t ≡ 3
    STEP(0, 1, 3, sA, sB, 1, 1)               // t ≡ 0
  }
  STEP(1, 2, 0, sB, sA, 1, 1)                 // t = 29
  STEP(0, 3, 1, sA, sB, 1, 1)                 // t = 30
  STEP(1, 0, 2, sB, sA, 0, 1)                 // t = 31 (no stage)

  // epilogue: finish tile 31 (sacc in sB, V in buf 3)
  SMAX_A(sB, 0); SMAX_A(sB, 1);
  TR_ALL(3);
  SMAX_B(sB, 0); SMAX_B(sB, 1);
  asm volatile("s_waitcnt lgkmcnt(0)" ::: "memory");
  __builtin_amdgcn_sched_barrier(0);
  PV_ALL();

  // normalize + store: O^T -> attb[row=q][col=h*64+d]; d = f*16+4g+r, q = q0+qc*16+c
#pragma unroll
  for (int qc = 0; qc < 2; ++qc) {
    const float inv = __builtin_amdgcn_rcpf(lacc[qc][0]);
    const size_t row = (size_t)(b * NN + q0 + qc * 16 + c);
#pragma unroll
    for (int f = 0; f < 4; ++f) {
      bf16x4 o;
#pragma unroll
      for (int r = 0; r < 4; ++r) o[r] = (bf16)(oacc[f][qc][r] * inv);
      *(bf16x4*)(attb + row * 1024 + h * 64 + f * 16 + 4 * g) = o;
    }
  }
}

// ---------------------------------------------------------------------------
extern "C" void kernel_launch(void* const* d_in, const int* in_sizes, int n_in,
                              void* d_out, int out_size, void* d_ws, size_t ws_size,
                              hipStream_t stream) {
  const float* x = (const float*)d_in[0];
  const float* wqkv = (const float*)d_in[1];
  const float* wout = (const float*)d_in[2];
  const float* bout = (const float*)d_in[3];

  char* ws = (char*)d_ws;
  bf16* xb   = (bf16*)(ws);
  bf16* wqb  = (bf16*)(ws + 8388608);
  bf16* wob  = (bf16*)(ws + 14680064);
  bf16* qkvb = (bf16*)(ws + 16777216);
  bf16* attb = (bf16*)(ws + 41943040);

  convert_all<<<8192, 256, 0, stream>>>(x, wqkv, wout, xb, wqb, wob);
  gemm_bt<0><<<dim3(24, 32), 256, 0, stream>>>(xb, wqb, (void*)qkvb, nullptr, E3);
  flash_attn<<<512, 256, 0, stream>>>(qkvb, attb);
  gemm_bt<1><<<dim3(8, 32), 256, 0, stream>>>(attb, wob, d_out, bout, DIMM);
}